// Round 4
// baseline (293.943 us; speedup 1.0000x reference)
//
#include <hip/hip_runtime.h>
#include <math.h>

constexpr int DIM = 64;
constexpr int S = 8;
constexpr int WPB = 8;                 // waves per block
constexpr int BLOCK = WPB * 64;
constexpr int GRID = 1024;             // 4 blocks/CU resident; grid-stride over batch
constexpr int WSTR = 68;               // W^T LDS row stride (measured ~0 conflicts in R2)

// readlane: wave-uniform scalar extract on the VALU pipe (no ds_bpermute)
__device__ __forceinline__ float rl(float x, int l) {
    return __builtin_bit_cast(float, __builtin_amdgcn_readlane(__builtin_bit_cast(int, x), l));
}

// DPP quad-perm lane exchange (VALU pipe, not DS)
template <int CTRL>
__device__ __forceinline__ float dppx(float x) {
    return __builtin_bit_cast(float,
        __builtin_amdgcn_mov_dpp(__builtin_bit_cast(int, x), CTRL, 0xf, 0xf, true));
}
#define XOR1 0xB1   // quad_perm(1,0,3,2)
#define XOR2 0x4E   // quad_perm(2,3,0,1)

// 8-way softmax over lanes' (lane&7) scores; returns per-lane weight
// (lane k mod 8 holds w[k]); extract with rl().
__device__ __forceinline__ float octet_softmax_w(float sc) {
    float m = sc;
    m = fmaxf(m, dppx<XOR1>(m));
    m = fmaxf(m, dppx<XOR2>(m));
    m = fmaxf(m, __shfl_xor(m, 4));
    float e = __expf(sc - m);
    float s = e;
    s += dppx<XOR1>(s);
    s += dppx<XOR2>(s);
    s += __shfl_xor(s, 4);
    return e / s;
}

__global__ __launch_bounds__(BLOCK)
void sestkgcn_kernel(
    const int*   __restrict__ u_idx,
    const int*   __restrict__ v_idx,
    const float* __restrict__ usr_feat,
    const float* __restrict__ item_feat,
    const float* __restrict__ rel_feat,
    const int*   __restrict__ neigh_uu,
    const float* __restrict__ neigh_uu_st,
    const int*   __restrict__ neigh_ui,
    const float* __restrict__ neigh_ui_rat,
    const float* __restrict__ neigh_ui_vot,
    const float* __restrict__ neigh_ui_tim,
    const int*   __restrict__ neigh_iu,
    const float* __restrict__ neigh_iu_rat,
    const float* __restrict__ neigh_iu_vot,
    const float* __restrict__ neigh_iu_tim,
    const int*   __restrict__ neigh_ii,
    const int*   __restrict__ neigh_ir,
    const float* __restrict__ Wu,
    const float* __restrict__ bu,
    const float* __restrict__ Wv,
    const float* __restrict__ bv,
    float*       __restrict__ out,
    int n)
{
    __shared__ float sWuT[DIM * WSTR];
    __shared__ float sWvT[DIM * WSTR];
    __shared__ float sbu[DIM];
    __shared__ float sbv[DIM];

    const int tid = threadIdx.x;
    for (int i = tid; i < DIM * DIM; i += BLOCK) {
        const int d_ = i >> 6, j_ = i & 63;
        sWuT[j_ * WSTR + d_] = Wu[i];
        sWvT[j_ * WSTR + d_] = Wv[i];
    }
    if (tid < DIM) { sbu[tid] = bu[tid]; sbv[tid] = bv[tid]; }
    __syncthreads();

    const int wave = tid >> 6;
    const int lane = tid & 63;
    const int ls   = lane & 7;

    const float4* wuT = (const float4*)&sWuT[lane * WSTR];
    const float4* wvT = (const float4*)&sWvT[lane * WSTR];
    const float bu_l = sbu[lane];
    const float bv_l = sbv[lane];

    const int stride = GRID * WPB;
    int b = blockIdx.x * WPB + wave;
    if (b >= n) return;

    int u = u_idx[b];
    int v = v_idx[b];

    while (b < n) {
        // prefetch next iteration's indices (breaks one level of the dep chain)
        const int b2 = b + stride;
        const int bc = (b2 < n) ? b2 : b;
        const int u_nxt = u_idx[bc];
        const int v_nxt = v_idx[bc];

        const unsigned u8 = (unsigned)u << 3, v8 = (unsigned)v << 3;

        const float u_d = usr_feat[((unsigned)u << 6) | (unsigned)lane];
        const float v_d = item_feat[((unsigned)v << 6) | (unsigned)lane];

        // per-lane scores (s = lane&7)
        const float sc_uu = neigh_uu_st[u8 + ls];
        const float sc_ui = neigh_ui_rat[u8 + ls] * neigh_ui_vot[u8 + ls] * neigh_ui_tim[u8 + ls];
        const float sc_iu = neigh_iu_rat[v8 + ls] * neigh_iu_vot[v8 + ls] * neigh_iu_tim[v8 + ls];

        // ---------------- user side ----------------
        float agg_uu = 0.f;
        {
            const float w = octet_softmax_w(sc_uu);
            const int4 i0 = ((const int4*)(neigh_uu + u8))[0];
            const int4 i1 = ((const int4*)(neigh_uu + u8))[1];
            const int ni[S] = {i0.x, i0.y, i0.z, i0.w, i1.x, i1.y, i1.z, i1.w};
            float r[S];
            #pragma unroll
            for (int s = 0; s < S; s++) r[s] = usr_feat[((unsigned)ni[s] << 6) | (unsigned)lane];
            #pragma unroll
            for (int s = 0; s < S; s++) agg_uu = fmaf(rl(w, s), r[s], agg_uu);
        }

        float agg_ui = 0.f;
        {
            const float w = octet_softmax_w(sc_ui);
            const int4 i0 = ((const int4*)(neigh_ui + u8))[0];
            const int4 i1 = ((const int4*)(neigh_ui + u8))[1];
            const int ni[S] = {i0.x, i0.y, i0.z, i0.w, i1.x, i1.y, i1.z, i1.w};
            float r[S];
            #pragma unroll
            for (int s = 0; s < S; s++) r[s] = item_feat[((unsigned)ni[s] << 6) | (unsigned)lane];
            #pragma unroll
            for (int s = 0; s < S; s++) agg_ui = fmaf(rl(w, s), r[s], agg_ui);
        }

        // user_h = relu(x @ Wu + bu): x broadcast via readlane, W via LDS b128
        float hu;
        {
            const float x = u_d + agg_uu + agg_ui;
            float a0 = 0.f, a1 = 0.f, a2 = 0.f, a3 = 0.f;
            #pragma unroll
            for (int k = 0; k < DIM / 4; k++) {
                const float4 wv = wuT[k];
                a0 = fmaf(rl(x, 4 * k + 0), wv.x, a0);
                a1 = fmaf(rl(x, 4 * k + 1), wv.y, a1);
                a2 = fmaf(rl(x, 4 * k + 2), wv.z, a2);
                a3 = fmaf(rl(x, 4 * k + 3), wv.w, a3);
            }
            hu = fmaxf((a0 + a1) + (a2 + a3) + bu_l, 0.f);
        }

        // ---------------- item side ----------------
        float agg_iu = 0.f;
        {
            const float w = octet_softmax_w(sc_iu);
            const int4 i0 = ((const int4*)(neigh_iu + v8))[0];
            const int4 i1 = ((const int4*)(neigh_iu + v8))[1];
            const int ni[S] = {i0.x, i0.y, i0.z, i0.w, i1.x, i1.y, i1.z, i1.w};
            float r[S];
            #pragma unroll
            for (int s = 0; s < S; s++) r[s] = usr_feat[((unsigned)ni[s] << 6) | (unsigned)lane];
            #pragma unroll
            for (int s = 0; s < S; s++) agg_iu = fmaf(rl(w, s), r[s], agg_iu);
        }

        // KG attention: merge 8 dot-products so lane holds total for s=lane&7
        float w_ii;
        {
            const int4 r0 = ((const int4*)(neigh_ir + v8))[0];
            const int4 r1 = ((const int4*)(neigh_ir + v8))[1];
            const int nr[S] = {r0.x, r0.y, r0.z, r0.w, r1.x, r1.y, r1.z, r1.w};
            float p[S];
            #pragma unroll
            for (int s = 0; s < S; s++) p[s] = u_d * rel_feat[((unsigned)nr[s] << 6) | (unsigned)lane];

            float m1[4];
            #pragma unroll
            for (int i = 0; i < 4; i++) {
                float lo = (lane & 1) ? p[2 * i + 1] : p[2 * i];
                float hi = (lane & 1) ? p[2 * i]     : p[2 * i + 1];
                m1[i] = lo + dppx<XOR1>(hi);
            }
            float m2[2];
            #pragma unroll
            for (int i = 0; i < 2; i++) {
                float lo = (lane & 2) ? m1[2 * i + 1] : m1[2 * i];
                float hi = (lane & 2) ? m1[2 * i]     : m1[2 * i + 1];
                m2[i] = lo + dppx<XOR2>(hi);
            }
            float lo = (lane & 4) ? m2[1] : m2[0];
            float hi = (lane & 4) ? m2[0] : m2[1];
            float att = lo + __shfl_xor(hi, 4);
            att += __shfl_xor(att, 8);
            att += __shfl_xor(att, 16);
            att += __shfl_xor(att, 32);
            w_ii = octet_softmax_w(att);
        }
        float agg_ii = 0.f;
        {
            const int4 i0 = ((const int4*)(neigh_ii + v8))[0];
            const int4 i1 = ((const int4*)(neigh_ii + v8))[1];
            const int ni[S] = {i0.x, i0.y, i0.z, i0.w, i1.x, i1.y, i1.z, i1.w};
            float r[S];
            #pragma unroll
            for (int s = 0; s < S; s++) r[s] = item_feat[((unsigned)ni[s] << 6) | (unsigned)lane];
            #pragma unroll
            for (int s = 0; s < S; s++) agg_ii = fmaf(rl(w_ii, s), r[s], agg_ii);
        }

        // item_h = relu(x @ Wv + bv)
        float hv;
        {
            const float x = v_d + agg_iu + agg_ii;
            float a0 = 0.f, a1 = 0.f, a2 = 0.f, a3 = 0.f;
            #pragma unroll
            for (int k = 0; k < DIM / 4; k++) {
                const float4 wv = wvT[k];
                a0 = fmaf(rl(x, 4 * k + 0), wv.x, a0);
                a1 = fmaf(rl(x, 4 * k + 1), wv.y, a1);
                a2 = fmaf(rl(x, 4 * k + 2), wv.z, a2);
                a3 = fmaf(rl(x, 4 * k + 3), wv.w, a3);
            }
            hv = fmaxf((a0 + a1) + (a2 + a3) + bv_l, 0.f);
        }

        // score = sigmoid(dot(user_h, item_h)) * 5
        float p = hu * hv;
        p += dppx<XOR1>(p);
        p += dppx<XOR2>(p);
        p += __shfl_xor(p, 4);
        p += __shfl_xor(p, 8);
        p += __shfl_xor(p, 16);
        p += __shfl_xor(p, 32);
        if (lane == 0) out[b] = 5.0f / (1.0f + __expf(-p));

        b = b2;
        u = u_nxt;
        v = v_nxt;
    }
}

extern "C" void kernel_launch(void* const* d_in, const int* in_sizes, int n_in,
                              void* d_out, int out_size, void* d_ws, size_t ws_size,
                              hipStream_t stream) {
    const int*   u_idx        = (const int*)  d_in[0];
    const int*   v_idx        = (const int*)  d_in[1];
    const float* usr_feat     = (const float*)d_in[2];
    const float* item_feat    = (const float*)d_in[3];
    const float* rel_feat     = (const float*)d_in[4];
    const int*   neigh_uu     = (const int*)  d_in[5];
    const float* neigh_uu_st  = (const float*)d_in[6];
    const int*   neigh_ui     = (const int*)  d_in[7];
    const float* neigh_ui_rat = (const float*)d_in[8];
    const float* neigh_ui_vot = (const float*)d_in[9];
    const float* neigh_ui_tim = (const float*)d_in[10];
    const int*   neigh_iu     = (const int*)  d_in[11];
    const float* neigh_iu_rat = (const float*)d_in[12];
    const float* neigh_iu_vot = (const float*)d_in[13];
    const float* neigh_iu_tim = (const float*)d_in[14];
    const int*   neigh_ii     = (const int*)  d_in[15];
    const int*   neigh_ir     = (const int*)  d_in[16];
    const float* Wu           = (const float*)d_in[17];
    const float* bu           = (const float*)d_in[18];
    const float* Wv           = (const float*)d_in[19];
    const float* bv           = (const float*)d_in[20];
    float*       out          = (float*)d_out;

    const int n = in_sizes[0];
    int blocks = (n + WPB - 1) / WPB;
    if (blocks > GRID) blocks = GRID;
    sestkgcn_kernel<<<blocks, BLOCK, 0, stream>>>(
        u_idx, v_idx, usr_feat, item_feat, rel_feat,
        neigh_uu, neigh_uu_st, neigh_ui, neigh_ui_rat, neigh_ui_vot, neigh_ui_tim,
        neigh_iu, neigh_iu_rat, neigh_iu_vot, neigh_iu_tim, neigh_ii, neigh_ir,
        Wu, bu, Wv, bv, out, n);
}

// Round 5
// 292.509 us; speedup vs baseline: 1.0049x; 1.0049x over previous
//
#include <hip/hip_runtime.h>
#include <math.h>

constexpr int DIM = 64;
constexpr int S = 8;
constexpr int WPB = 8;                 // waves per block
constexpr int BLOCK = WPB * 64;
constexpr int GRID = 1024;             // grid-stride; each wave handles pairs of batch elements
constexpr int WSTR = 68;               // W^T LDS row stride (measured ~0 conflicts in R2)

__device__ __forceinline__ int rfl(int x) { return __builtin_amdgcn_readfirstlane(x); }

// DPP quad-perm lane exchange (VALU pipe, not DS) — verified correct in R3
template <int CTRL>
__device__ __forceinline__ float dppx(float x) {
    return __builtin_bit_cast(float,
        __builtin_amdgcn_mov_dpp(__builtin_bit_cast(int, x), CTRL, 0xf, 0xf, true));
}
#define XOR1 0xB1   // quad_perm(1,0,3,2)
#define XOR2 0x4E   // quad_perm(2,3,0,1)

__global__ __launch_bounds__(BLOCK, 4)
void sestkgcn_kernel(
    const int*   __restrict__ u_idx,
    const int*   __restrict__ v_idx,
    const float* __restrict__ usr_feat,
    const float* __restrict__ item_feat,
    const float* __restrict__ rel_feat,
    const int*   __restrict__ neigh_uu,
    const float* __restrict__ neigh_uu_st,
    const int*   __restrict__ neigh_ui,
    const float* __restrict__ neigh_ui_rat,
    const float* __restrict__ neigh_ui_vot,
    const float* __restrict__ neigh_ui_tim,
    const int*   __restrict__ neigh_iu,
    const float* __restrict__ neigh_iu_rat,
    const float* __restrict__ neigh_iu_vot,
    const float* __restrict__ neigh_iu_tim,
    const int*   __restrict__ neigh_ii,
    const int*   __restrict__ neigh_ir,
    const float* __restrict__ Wu,
    const float* __restrict__ bu,
    const float* __restrict__ Wv,
    const float* __restrict__ bv,
    float*       __restrict__ out,
    int n)
{
    __shared__ float sWuT[DIM * WSTR];
    __shared__ float sWvT[DIM * WSTR];
    __shared__ float sbu[DIM];
    __shared__ float sbv[DIM];
    __shared__ float xpack[WPB][2 * DIM];   // per-wave packed (k, b-slot) x for paired GEMV
    __shared__ float estrip[WPB][2][8];     // per-wave KG softmax numerators

    const int tid = threadIdx.x;
    for (int i = tid; i < DIM * DIM; i += BLOCK) {
        const int d_ = i >> 6, j_ = i & 63;
        sWuT[j_ * WSTR + d_] = Wu[i];
        sWvT[j_ * WSTR + d_] = Wv[i];
    }
    if (tid < DIM) { sbu[tid] = bu[tid]; sbv[tid] = bv[tid]; }
    __syncthreads();

    const int wave = tid >> 6;
    const int lane = tid & 63;

    const float4* wuT = (const float4*)&sWuT[lane * WSTR];
    const float4* wvT = (const float4*)&sWvT[lane * WSTR];
    const float bu_l = sbu[lane];
    const float bv_l = sbv[lane];
    float*       xp  = xpack[wave];
    const float4* xq = (const float4*)xp;

    const int pstride = GRID * WPB * 2;
    for (int b0 = (blockIdx.x * WPB + wave) * 2; b0 < n; b0 += pstride) {
        const int b1 = b0 + 1;
        const bool has1 = (b1 < n);

        float xu[2], xv[2];

        #pragma unroll
        for (int t = 0; t < 2; t++) {
            const int bb = t ? (has1 ? b1 : b0) : b0;
            const int u = rfl(u_idx[bb]);
            const int v = rfl(v_idx[bb]);
            const float u_d = usr_feat[((size_t)u << 6) + lane];
            const float v_d = item_feat[((size_t)v << 6) + lane];

            // ---- user: social neighbors (scores uniform -> per-lane redundant softmax) ----
            float agg_uu;
            {
                const float4 sA = ((const float4*)(neigh_uu_st + (size_t)u * S))[0];
                const float4 sB = ((const float4*)(neigh_uu_st + (size_t)u * S))[1];
                const float sc[S] = {sA.x, sA.y, sA.z, sA.w, sB.x, sB.y, sB.z, sB.w};
                float m = sc[0];
                #pragma unroll
                for (int s = 1; s < S; s++) m = fmaxf(m, sc[s]);
                float e[S], sum = 0.f;
                #pragma unroll
                for (int s = 0; s < S; s++) { e[s] = __expf(sc[s] - m); sum += e[s]; }
                const float inv = 1.f / sum;
                const int4 i0 = ((const int4*)(neigh_uu + (size_t)u * S))[0];
                const int4 i1 = ((const int4*)(neigh_uu + (size_t)u * S))[1];
                const int ni[S] = {i0.x, i0.y, i0.z, i0.w, i1.x, i1.y, i1.z, i1.w};
                float acc = 0.f;
                #pragma unroll
                for (int s = 0; s < S; s++)
                    acc = fmaf(e[s], usr_feat[((size_t)rfl(ni[s]) << 6) + lane], acc);
                agg_uu = acc * inv;
            }

            // ---- user: interacted items ----
            float agg_ui;
            {
                const float4 rA = ((const float4*)(neigh_ui_rat + (size_t)u * S))[0];
                const float4 rB = ((const float4*)(neigh_ui_rat + (size_t)u * S))[1];
                const float4 vA = ((const float4*)(neigh_ui_vot + (size_t)u * S))[0];
                const float4 vB = ((const float4*)(neigh_ui_vot + (size_t)u * S))[1];
                const float4 tA = ((const float4*)(neigh_ui_tim + (size_t)u * S))[0];
                const float4 tB = ((const float4*)(neigh_ui_tim + (size_t)u * S))[1];
                const float sc[S] = {rA.x*vA.x*tA.x, rA.y*vA.y*tA.y, rA.z*vA.z*tA.z, rA.w*vA.w*tA.w,
                                     rB.x*vB.x*tB.x, rB.y*vB.y*tB.y, rB.z*vB.z*tB.z, rB.w*vB.w*tB.w};
                float m = sc[0];
                #pragma unroll
                for (int s = 1; s < S; s++) m = fmaxf(m, sc[s]);
                float e[S], sum = 0.f;
                #pragma unroll
                for (int s = 0; s < S; s++) { e[s] = __expf(sc[s] - m); sum += e[s]; }
                const float inv = 1.f / sum;
                const int4 i0 = ((const int4*)(neigh_ui + (size_t)u * S))[0];
                const int4 i1 = ((const int4*)(neigh_ui + (size_t)u * S))[1];
                const int ni[S] = {i0.x, i0.y, i0.z, i0.w, i1.x, i1.y, i1.z, i1.w};
                float acc = 0.f;
                #pragma unroll
                for (int s = 0; s < S; s++)
                    acc = fmaf(e[s], item_feat[((size_t)rfl(ni[s]) << 6) + lane], acc);
                agg_ui = acc * inv;
            }

            // ---- item: interacting users ----
            float agg_iu;
            {
                const float4 rA = ((const float4*)(neigh_iu_rat + (size_t)v * S))[0];
                const float4 rB = ((const float4*)(neigh_iu_rat + (size_t)v * S))[1];
                const float4 vA = ((const float4*)(neigh_iu_vot + (size_t)v * S))[0];
                const float4 vB = ((const float4*)(neigh_iu_vot + (size_t)v * S))[1];
                const float4 tA = ((const float4*)(neigh_iu_tim + (size_t)v * S))[0];
                const float4 tB = ((const float4*)(neigh_iu_tim + (size_t)v * S))[1];
                const float sc[S] = {rA.x*vA.x*tA.x, rA.y*vA.y*tA.y, rA.z*vA.z*tA.z, rA.w*vA.w*tA.w,
                                     rB.x*vB.x*tB.x, rB.y*vB.y*tB.y, rB.z*vB.z*tB.z, rB.w*vB.w*tB.w};
                float m = sc[0];
                #pragma unroll
                for (int s = 1; s < S; s++) m = fmaxf(m, sc[s]);
                float e[S], sum = 0.f;
                #pragma unroll
                for (int s = 0; s < S; s++) { e[s] = __expf(sc[s] - m); sum += e[s]; }
                const float inv = 1.f / sum;
                const int4 i0 = ((const int4*)(neigh_iu + (size_t)v * S))[0];
                const int4 i1 = ((const int4*)(neigh_iu + (size_t)v * S))[1];
                const int ni[S] = {i0.x, i0.y, i0.z, i0.w, i1.x, i1.y, i1.z, i1.w};
                float acc = 0.f;
                #pragma unroll
                for (int s = 0; s < S; s++)
                    acc = fmaf(e[s], usr_feat[((size_t)rfl(ni[s]) << 6) + lane], acc);
                agg_iu = acc * inv;
            }

            // ---- item: KG neighbors, user-relation attention ----
            float agg_ii;
            {
                const int4 r0 = ((const int4*)(neigh_ir + (size_t)v * S))[0];
                const int4 r1 = ((const int4*)(neigh_ir + (size_t)v * S))[1];
                const int nr[S] = {r0.x, r0.y, r0.z, r0.w, r1.x, r1.y, r1.z, r1.w};
                float p[S];
                #pragma unroll
                for (int s = 0; s < S; s++)
                    p[s] = u_d * rel_feat[((size_t)rfl(nr[s]) << 6) + lane];

                float m1[4];
                #pragma unroll
                for (int i = 0; i < 4; i++) {
                    float lo = (lane & 1) ? p[2*i+1] : p[2*i];
                    float hi = (lane & 1) ? p[2*i]   : p[2*i+1];
                    m1[i] = lo + dppx<XOR1>(hi);
                }
                float m2[2];
                #pragma unroll
                for (int i = 0; i < 2; i++) {
                    float lo = (lane & 2) ? m1[2*i+1] : m1[2*i];
                    float hi = (lane & 2) ? m1[2*i]   : m1[2*i+1];
                    m2[i] = lo + dppx<XOR2>(hi);
                }
                float lo = (lane & 4) ? m2[1] : m2[0];
                float hi = (lane & 4) ? m2[0] : m2[1];
                float att = lo + __shfl_xor(hi, 4);
                att += __shfl_xor(att, 8);
                att += __shfl_xor(att, 16);
                att += __shfl_xor(att, 32);
                // per-lane octet softmax numerator (s = lane&7), 1/sum replicated
                float mm = att;
                mm = fmaxf(mm, dppx<XOR1>(mm));
                mm = fmaxf(mm, dppx<XOR2>(mm));
                mm = fmaxf(mm, __shfl_xor(mm, 4));
                const float e = __expf(att - mm);
                float ssum = e;
                ssum += dppx<XOR1>(ssum);
                ssum += dppx<XOR2>(ssum);
                ssum += __shfl_xor(ssum, 4);
                const float inv = 1.f / ssum;
                if (lane < 8) estrip[wave][t][lane] = e;
                __threadfence_block();
                const float4 eA = ((const float4*)estrip[wave][t])[0];
                const float4 eB = ((const float4*)estrip[wave][t])[1];
                const float ee[S] = {eA.x, eA.y, eA.z, eA.w, eB.x, eB.y, eB.z, eB.w};
                const int4 i0 = ((const int4*)(neigh_ii + (size_t)v * S))[0];
                const int4 i1 = ((const int4*)(neigh_ii + (size_t)v * S))[1];
                const int ni[S] = {i0.x, i0.y, i0.z, i0.w, i1.x, i1.y, i1.z, i1.w};
                float acc = 0.f;
                #pragma unroll
                for (int s = 0; s < S; s++)
                    acc = fmaf(ee[s], item_feat[((size_t)rfl(ni[s]) << 6) + lane], acc);
                agg_ii = acc * inv;
            }

            xu[t] = u_d + agg_uu + agg_ui;
            xv[t] = v_d + agg_iu + agg_ii;
        }

        // ---- paired GEMV: user side (W b128 read shared by both b's) ----
        ((float2*)xp)[lane] = make_float2(xu[0], xu[1]);
        __threadfence_block();
        float a0=0.f,a1=0.f,a2=0.f,a3=0.f, c0=0.f,c1=0.f,c2=0.f,c3=0.f;
        #pragma unroll
        for (int k = 0; k < DIM / 4; k++) {
            const float4 wv = wuT[k];
            const float4 xA = xq[2*k];      // {x0[4k],x1[4k],x0[4k+1],x1[4k+1]}
            const float4 xB = xq[2*k+1];    // {x0[4k+2],x1[4k+2],x0[4k+3],x1[4k+3]}
            a0 = fmaf(xA.x, wv.x, a0); a1 = fmaf(xA.z, wv.y, a1);
            a2 = fmaf(xB.x, wv.z, a2); a3 = fmaf(xB.z, wv.w, a3);
            c0 = fmaf(xA.y, wv.x, c0); c1 = fmaf(xA.w, wv.y, c1);
            c2 = fmaf(xB.y, wv.z, c2); c3 = fmaf(xB.w, wv.w, c3);
        }
        const float hu0 = fmaxf((a0+a1)+(a2+a3)+bu_l, 0.f);
        const float hu1 = fmaxf((c0+c1)+(c2+c3)+bu_l, 0.f);

        // ---- paired GEMV: item side ----
        __threadfence_block();
        ((float2*)xp)[lane] = make_float2(xv[0], xv[1]);
        __threadfence_block();
        float d0=0.f,d1=0.f,d2=0.f,d3=0.f, g0=0.f,g1=0.f,g2=0.f,g3=0.f;
        #pragma unroll
        for (int k = 0; k < DIM / 4; k++) {
            const float4 wv = wvT[k];
            const float4 xA = xq[2*k];
            const float4 xB = xq[2*k+1];
            d0 = fmaf(xA.x, wv.x, d0); d1 = fmaf(xA.z, wv.y, d1);
            d2 = fmaf(xB.x, wv.z, d2); d3 = fmaf(xB.z, wv.w, d3);
            g0 = fmaf(xA.y, wv.x, g0); g1 = fmaf(xA.w, wv.y, g1);
            g2 = fmaf(xB.y, wv.z, g2); g3 = fmaf(xB.w, wv.w, g3);
        }
        const float hv0 = fmaxf((d0+d1)+(d2+d3)+bv_l, 0.f);
        const float hv1 = fmaxf((g0+g1)+(g2+g3)+bv_l, 0.f);

        // ---- paired dot + sigmoid: parity-split shared reduction tree ----
        const float p0 = hu0 * hv0, p1 = hu1 * hv1;
        float s0 = p0 + dppx<XOR1>(p0);
        float s1 = p1 + dppx<XOR1>(p1);
        float tt = (lane & 1) ? s1 : s0;
        tt += dppx<XOR2>(tt);
        tt += __shfl_xor(tt, 4);
        tt += __shfl_xor(tt, 8);
        tt += __shfl_xor(tt, 16);
        tt += __shfl_xor(tt, 32);
        // even lanes hold sum(p0), odd lanes hold sum(p1)
        if (lane == 0) out[b0] = 5.f / (1.f + __expf(-tt));
        else if (lane == 1 && has1) out[b1] = 5.f / (1.f + __expf(-tt));
    }
}

extern "C" void kernel_launch(void* const* d_in, const int* in_sizes, int n_in,
                              void* d_out, int out_size, void* d_ws, size_t ws_size,
                              hipStream_t stream) {
    const int*   u_idx        = (const int*)  d_in[0];
    const int*   v_idx        = (const int*)  d_in[1];
    const float* usr_feat     = (const float*)d_in[2];
    const float* item_feat    = (const float*)d_in[3];
    const float* rel_feat     = (const float*)d_in[4];
    const int*   neigh_uu     = (const int*)  d_in[5];
    const float* neigh_uu_st  = (const float*)d_in[6];
    const int*   neigh_ui     = (const int*)  d_in[7];
    const float* neigh_ui_rat = (const float*)d_in[8];
    const float* neigh_ui_vot = (const float*)d_in[9];
    const float* neigh_ui_tim = (const float*)d_in[10];
    const int*   neigh_iu     = (const int*)  d_in[11];
    const float* neigh_iu_rat = (const float*)d_in[12];
    const float* neigh_iu_vot = (const float*)d_in[13];
    const float* neigh_iu_tim = (const float*)d_in[14];
    const int*   neigh_ii     = (const int*)  d_in[15];
    const int*   neigh_ir     = (const int*)  d_in[16];
    const float* Wu           = (const float*)d_in[17];
    const float* bu           = (const float*)d_in[18];
    const float* Wv           = (const float*)d_in[19];
    const float* bv           = (const float*)d_in[20];
    float*       out          = (float*)d_out;

    const int n = in_sizes[0];
    int blocks = (n + WPB * 2 - 1) / (WPB * 2);
    if (blocks > GRID) blocks = GRID;
    sestkgcn_kernel<<<blocks, BLOCK, 0, stream>>>(
        u_idx, v_idx, usr_feat, item_feat, rel_feat,
        neigh_uu, neigh_uu_st, neigh_ui, neigh_ui_rat, neigh_ui_vot, neigh_ui_tim,
        neigh_iu, neigh_iu_rat, neigh_iu_vot, neigh_iu_tim, neigh_ii, neigh_ir,
        Wu, bu, Wv, bv, out, n);
}